// Round 1
// baseline (1124.391 us; speedup 1.0000x reference)
//
#include <hip/hip_runtime.h>
#include <math.h>

// Fully-fused: conv1/conv2/conv3 + pool + fc + normalize + 8-qubit qsim + MLP classifier.
// 256 threads = 4 waves per block; 16 samples per block (4 per wave).
// All LDS dependencies are intra-wave -> no __syncthreads in the main body.

#define WR_SZ 1856   // per-wave scratch floats

__global__ __launch_bounds__(256, 3)
void fused_all(const float* __restrict__ x,
               const float* __restrict__ c1w, const float* __restrict__ c1b,
               const float* __restrict__ c2w, const float* __restrict__ c2b,
               const float* __restrict__ c3w, const float* __restrict__ c3b,
               const float* __restrict__ fcw, const float* __restrict__ fcb,
               const float* __restrict__ qw,
               const float* __restrict__ w1, const float* __restrict__ b1,
               const float* __restrict__ w2, const float* __restrict__ b2,
               const float* __restrict__ w3, const float* __restrict__ b3,
               const float* __restrict__ w4, const float* __restrict__ b4,
               const float* __restrict__ w5, const float* __restrict__ b5,
               float* __restrict__ out, int B)
{
    __shared__ float wreg[4][WR_SZ];
    __shared__ float featL[16][272];   // padded stride 272 -> 2-way (free) LDS banking
    __shared__ float qc[56];
    __shared__ float qs[56];

    const int tid  = threadIdx.x;
    const int lane = tid & 63;
    const int wv   = tid >> 6;

    if (tid < 56) {
        float th = 0.5f * qw[tid];
        qc[tid] = cosf(th);
        qs[tid] = sinf(th);
    }
    __syncthreads();

    float* wr = wreg[wv];
    const int base = blockIdx.x * 16;

    // ================= Phase 1: convs + pool + fc + normalize (per wave, 4 samples) =================
    for (int smp = 0; smp < 4; ++smp) {
        const int sib = wv * 4 + smp;
        const int sample = base + sib;
        if (sample >= B) break;

        float* c1p = wr;          // 768 = 3*16*16 (conv1 out, pad 1)
        float* pin = wr + 768;    // 1024 = 32*32  (input, pad 2)

        for (int i = lane; i < 1024; i += 64) pin[i] = 0.f;
        {
            const float4* xs = (const float4*)(x + (size_t)sample * 784);
            #pragma unroll
            for (int t = 0; t < 4; ++t) {
                int i4 = t * 64 + lane;
                if (i4 < 196) {
                    float4 v = xs[i4];
                    int r = i4 / 7;          // 28 cols = 7 float4/row, never wraps
                    int c = (i4 % 7) * 4;
                    float* dst = pin + (r + 2) * 32 + (c + 2);
                    dst[0] = v.x; dst[1] = v.y; dst[2] = v.z; dst[3] = v.w;
                }
            }
        }
        for (int i = lane; i < 768; i += 64) c1p[i] = 0.f;

        // ---- conv1: 1x28x28 -> 3x14x14, k5 s2 p2 ----
        #pragma unroll
        for (int t = 0; t < 4; ++t) {
            int p = t * 64 + lane;
            bool valid = p < 196;
            int pp = valid ? p : 0;
            int y = pp / 14, xx = pp % 14;
            const float* pr = pin + (2 * y) * 32 + 2 * xx;
            float win[25];
            #pragma unroll
            for (int ky = 0; ky < 5; ++ky)
                #pragma unroll
                for (int kx = 0; kx < 5; ++kx)
                    win[ky * 5 + kx] = pr[ky * 32 + kx];
            #pragma unroll
            for (int c = 0; c < 3; ++c) {
                float acc = c1b[c];
                #pragma unroll
                for (int k = 0; k < 25; ++k)
                    acc = fmaf(win[k], c1w[c * 25 + k], acc);
                if (valid) c1p[c * 256 + (y + 1) * 16 + (xx + 1)] = fmaxf(acc, 0.f);
            }
        }

        // ---- conv2: 3x14x14 -> 6x7x7, k3 s2 p1 ----
        float* c2p = wr + 768;   // 486 = 6*9*9 (reuses pin space; pin dead)
        for (int i = lane; i < 486; i += 64) c2p[i] = 0.f;
        {
            int p = lane;
            bool valid = p < 49;
            int pp = valid ? p : 0;
            int y = pp / 7, xx = pp % 7;
            float acc[6];
            #pragma unroll
            for (int c = 0; c < 6; ++c) acc[c] = c2b[c];
            #pragma unroll
            for (int ic = 0; ic < 3; ++ic) {
                const float* pr = c1p + ic * 256 + (2 * y) * 16 + 2 * xx;
                float win[9];
                #pragma unroll
                for (int ky = 0; ky < 3; ++ky)
                    #pragma unroll
                    for (int kx = 0; kx < 3; ++kx)
                        win[ky * 3 + kx] = pr[ky * 16 + kx];
                #pragma unroll
                for (int c = 0; c < 6; ++c)
                    #pragma unroll
                    for (int k = 0; k < 9; ++k)
                        acc[c] = fmaf(win[k], c2w[c * 27 + ic * 9 + k], acc[c]);
            }
            if (valid) {
                #pragma unroll
                for (int c = 0; c < 6; ++c)
                    c2p[c * 81 + (y + 1) * 9 + (xx + 1)] = fmaxf(acc[c], 0.f);
            }
        }

        // ---- conv3: 6x7x7 -> 12x7x7, k3 s1 p1 ----
        float* c3 = wr + 1256;   // 588 = 12*49
        {
            int p = lane;
            bool valid = p < 49;
            int pp = valid ? p : 0;
            int y = pp / 7, xx = pp % 7;
            float acc[12];
            #pragma unroll
            for (int c = 0; c < 12; ++c) acc[c] = c3b[c];
            #pragma unroll
            for (int ic = 0; ic < 6; ++ic) {
                const float* pr = c2p + ic * 81 + y * 9 + xx;
                float win[9];
                #pragma unroll
                for (int ky = 0; ky < 3; ++ky)
                    #pragma unroll
                    for (int kx = 0; kx < 3; ++kx)
                        win[ky * 3 + kx] = pr[ky * 9 + kx];
                #pragma unroll
                for (int c = 0; c < 12; ++c)
                    #pragma unroll
                    for (int k = 0; k < 9; ++k)
                        acc[c] = fmaf(win[k], c3w[c * 54 + ic * 9 + k], acc[c]);
            }
            if (valid) {
                #pragma unroll
                for (int c = 0; c < 12; ++c)
                    c3[c * 49 + p] = fmaxf(acc[c], 0.f);
            }
        }

        // ---- adaptive pool (overlapping 4x4 bins) -> wr[0..48) ----
        {
            int o = lane;
            if (o < 48) {
                int c = o >> 2, i = (o >> 1) & 1, j = o & 1;
                int ri = i * 3, cj = j * 3;
                float s = 0.f;
                #pragma unroll
                for (int dy = 0; dy < 4; ++dy)
                    #pragma unroll
                    for (int dx = 0; dx < 4; ++dx)
                        s += c3[c * 49 + (ri + dy) * 7 + (cj + dx)];
                wr[o] = s * (1.f / 16.f);
            }
        }

        // ---- fc 48->256 + relu + L2-normalize -> featL[sib] ----
        {
            const int o0 = lane * 4;
            const float4* wr0 = (const float4*)(fcw + (o0 + 0) * 48);
            const float4* wr1 = (const float4*)(fcw + (o0 + 1) * 48);
            const float4* wr2 = (const float4*)(fcw + (o0 + 2) * 48);
            const float4* wr3 = (const float4*)(fcw + (o0 + 3) * 48);
            float a0 = 0.f, a1 = 0.f, a2 = 0.f, a3 = 0.f;
            #pragma unroll
            for (int kc = 0; kc < 12; ++kc) {
                float4 pv = *(const float4*)(wr + kc * 4);
                float4 q0 = wr0[kc], q1 = wr1[kc], q2 = wr2[kc], q3 = wr3[kc];
                a0 = fmaf(pv.x, q0.x, a0); a0 = fmaf(pv.y, q0.y, a0);
                a0 = fmaf(pv.z, q0.z, a0); a0 = fmaf(pv.w, q0.w, a0);
                a1 = fmaf(pv.x, q1.x, a1); a1 = fmaf(pv.y, q1.y, a1);
                a1 = fmaf(pv.z, q1.z, a1); a1 = fmaf(pv.w, q1.w, a1);
                a2 = fmaf(pv.x, q2.x, a2); a2 = fmaf(pv.y, q2.y, a2);
                a2 = fmaf(pv.z, q2.z, a2); a2 = fmaf(pv.w, q2.w, a2);
                a3 = fmaf(pv.x, q3.x, a3); a3 = fmaf(pv.y, q3.y, a3);
                a3 = fmaf(pv.z, q3.z, a3); a3 = fmaf(pv.w, q3.w, a3);
            }
            float4 fb = *(const float4*)(fcb + o0);
            float v0 = fmaxf(a0 + fb.x, 0.f);
            float v1 = fmaxf(a1 + fb.y, 0.f);
            float v2 = fmaxf(a2 + fb.z, 0.f);
            float v3 = fmaxf(a3 + fb.w, 0.f);
            float ss = v0 * v0 + v1 * v1 + v2 * v2 + v3 * v3;
            #pragma unroll
            for (int m = 1; m < 64; m <<= 1) ss += __shfl_xor(ss, m);
            float scale = 1.f / fmaxf(sqrtf(ss), 1e-12f);
            float4 fv;
            fv.x = v0 * scale; fv.y = v1 * scale; fv.z = v2 * scale; fv.w = v3 * scale;
            *(float4*)(&featL[sib][lane * 4]) = fv;
        }
    }

    // ================= Phase 2: qsim (16 lanes/sample) =================
    // amplitude index i (bit7=qubit0 ... bit0=qubit7): reg r = i>>4, lane w = i&15
    const int g = lane >> 4;
    const int w = lane & 15;
    const int sibq = wv * 4 + g;
    const int sampleq = base + sibq;

    float st[16];
    #pragma unroll
    for (int r = 0; r < 16; ++r) st[r] = featL[sibq][r * 16 + w];

    for (int layer = 0; layer < 7; ++layer) {
        // rotations qubits 0..3 (register bits 3..0)
        #pragma unroll
        for (int q = 0; q < 4; ++q) {
            float c = qc[layer * 8 + q];
            float s = qs[layer * 8 + q];
            const int m = 1 << (3 - q);
            #pragma unroll
            for (int r = 0; r < 16; ++r) {
                if (!(r & m)) {
                    float v0 = st[r], v1 = st[r | m];
                    st[r]     = fmaf(c, v0, -s * v1);
                    st[r | m] = fmaf(s, v0,  c * v1);
                }
            }
        }
        // rotations qubits 4..7 (lane bits 3..0)
        #pragma unroll
        for (int q = 4; q < 8; ++q) {
            float c = qc[layer * 8 + q];
            float s = qs[layer * 8 + q];
            const int lm = 1 << (7 - q);
            const float sg = (w & lm) ? s : -s;
            #pragma unroll
            for (int r = 0; r < 16; ++r) {
                float p = __shfl_xor(st[r], lm);
                st[r] = fmaf(c, st[r], sg * p);
            }
        }
        // CNOT chain q=0..6
        { float t;  // q=0: ctrl reg bit3, tgt reg bit2 (free renames)
          t = st[8];  st[8]  = st[12]; st[12] = t;
          t = st[9];  st[9]  = st[13]; st[13] = t;
          t = st[10]; st[10] = st[14]; st[14] = t;
          t = st[11]; st[11] = st[15]; st[15] = t; }
        { float t;  // q=1: ctrl reg bit2, tgt reg bit1
          t = st[4];  st[4]  = st[6];  st[6]  = t;
          t = st[5];  st[5]  = st[7];  st[7]  = t;
          t = st[12]; st[12] = st[14]; st[14] = t;
          t = st[13]; st[13] = st[15]; st[15] = t; }
        { float t;  // q=2: ctrl reg bit1, tgt reg bit0
          t = st[2];  st[2]  = st[3];  st[3]  = t;
          t = st[6];  st[6]  = st[7];  st[7]  = t;
          t = st[10]; st[10] = st[11]; st[11] = t;
          t = st[14]; st[14] = st[15]; st[15] = t; }
        // q=3: ctrl reg bit0, tgt lane bit3
        #pragma unroll
        for (int r = 1; r < 16; r += 2) st[r] = __shfl_xor(st[r], 8);
        // q=4: ctrl lane bit3, tgt lane bit2
        #pragma unroll
        for (int r = 0; r < 16; ++r) {
            float p = __shfl_xor(st[r], 4);
            st[r] = (w & 8) ? p : st[r];
        }
        // q=5: ctrl lane bit2, tgt lane bit1
        #pragma unroll
        for (int r = 0; r < 16; ++r) {
            float p = __shfl_xor(st[r], 2);
            st[r] = (w & 4) ? p : st[r];
        }
        // q=6: ctrl lane bit1, tgt lane bit0
        #pragma unroll
        for (int r = 0; r < 16; ++r) {
            float p = __shfl_xor(st[r], 1);
            st[r] = (w & 2) ? p : st[r];
        }
    }

    // measurement: <Z_0> = sum(bit7=0) - sum(bit7=1); bit7 = reg bit3
    float part = 0.f;
    #pragma unroll
    for (int r = 0; r < 8; ++r)  part += st[r] * st[r];
    #pragma unroll
    for (int r = 8; r < 16; ++r) part -= st[r] * st[r];
    #pragma unroll
    for (int m = 1; m < 16; m <<= 1) part += __shfl_xor(part, m);
    const float qout = part;

    // ================= Classifier: 1 -> 180 -> 140 -> 100 -> 50 -> 1 =================
    float* hA = wr + g * 336;      // 184 used
    float* hB = hA + 184;          // 144 used

    #pragma unroll
    for (int t = 0; t < 12; ++t) {
        int j = t * 16 + w;
        if (j < 180) hA[j] = fmaxf(fmaf(qout, w1[j], b1[j]), 0.f);
    }

    // layer2: 180 -> 140
    for (int t = 0; t < 9; ++t) {
        int j = t * 16 + w;
        int jj = (j < 140) ? j : 0;
        const float4* wrow = (const float4*)(w2 + jj * 180);
        float a0 = 0.f, a1 = 0.f, a2 = 0.f, a3 = 0.f;
        for (int kc = 0; kc < 45; ++kc) {
            float4 h4 = *(const float4*)(hA + kc * 4);
            float4 ww = wrow[kc];
            a0 = fmaf(h4.x, ww.x, a0);
            a1 = fmaf(h4.y, ww.y, a1);
            a2 = fmaf(h4.z, ww.z, a2);
            a3 = fmaf(h4.w, ww.w, a3);
        }
        if (j < 140) hB[j] = fmaxf((a0 + a1) + (a2 + a3) + b2[j], 0.f);
    }
    // layer3: 140 -> 100
    for (int t = 0; t < 7; ++t) {
        int j = t * 16 + w;
        int jj = (j < 100) ? j : 0;
        const float4* wrow = (const float4*)(w3 + jj * 140);
        float a0 = 0.f, a1 = 0.f, a2 = 0.f, a3 = 0.f;
        for (int kc = 0; kc < 35; ++kc) {
            float4 h4 = *(const float4*)(hB + kc * 4);
            float4 ww = wrow[kc];
            a0 = fmaf(h4.x, ww.x, a0);
            a1 = fmaf(h4.y, ww.y, a1);
            a2 = fmaf(h4.z, ww.z, a2);
            a3 = fmaf(h4.w, ww.w, a3);
        }
        if (j < 100) hA[j] = fmaxf((a0 + a1) + (a2 + a3) + b3[j], 0.f);
    }
    // layer4: 100 -> 50
    for (int t = 0; t < 4; ++t) {
        int j = t * 16 + w;
        int jj = (j < 50) ? j : 0;
        const float4* wrow = (const float4*)(w4 + jj * 100);
        float a0 = 0.f, a1 = 0.f, a2 = 0.f, a3 = 0.f;
        for (int kc = 0; kc < 25; ++kc) {
            float4 h4 = *(const float4*)(hA + kc * 4);
            float4 ww = wrow[kc];
            a0 = fmaf(h4.x, ww.x, a0);
            a1 = fmaf(h4.y, ww.y, a1);
            a2 = fmaf(h4.z, ww.z, a2);
            a3 = fmaf(h4.w, ww.w, a3);
        }
        if (j < 50) hB[j] = fmaxf((a0 + a1) + (a2 + a3) + b4[j], 0.f);
    }
    // layer5: 50 -> 1, sigmoid
    float p5 = 0.f;
    for (int k = w; k < 50; k += 16) p5 = fmaf(hB[k], w5[k], p5);
    #pragma unroll
    for (int m = 1; m < 16; m <<= 1) p5 += __shfl_xor(p5, m);
    float z = p5 + b5[0];
    float res = 1.f / (1.f + expf(-z));
    if (w == 0 && sampleq < B) out[sampleq] = res;
}

extern "C" void kernel_launch(void* const* d_in, const int* in_sizes, int n_in,
                              void* d_out, int out_size, void* d_ws, size_t ws_size,
                              hipStream_t stream) {
    const float* x   = (const float*)d_in[0];
    const float* c1w = (const float*)d_in[1];
    const float* c1b = (const float*)d_in[2];
    const float* c2w = (const float*)d_in[3];
    const float* c2b = (const float*)d_in[4];
    const float* c3w = (const float*)d_in[5];
    const float* c3b = (const float*)d_in[6];
    const float* fcw = (const float*)d_in[7];
    const float* fcb = (const float*)d_in[8];
    const float* qw  = (const float*)d_in[9];
    const float* w1  = (const float*)d_in[10];
    const float* b1  = (const float*)d_in[11];
    const float* w2  = (const float*)d_in[12];
    const float* b2  = (const float*)d_in[13];
    const float* w3  = (const float*)d_in[14];
    const float* b3  = (const float*)d_in[15];
    const float* w4  = (const float*)d_in[16];
    const float* b4  = (const float*)d_in[17];
    const float* w5  = (const float*)d_in[18];
    const float* b5  = (const float*)d_in[19];

    int B = in_sizes[0] / 784;
    int grid = (B + 15) / 16;
    fused_all<<<dim3(grid), dim3(256), 0, stream>>>(
        x, c1w, c1b, c2w, c2b, c3w, c3b, fcw, fcb, qw,
        w1, b1, w2, b2, w3, b3, w4, b4, w5, b5,
        (float*)d_out, B);
}

// Round 2
// 713.873 us; speedup vs baseline: 1.5751x; 1.5751x over previous
//
#include <hip/hip_runtime.h>
#include <math.h>

// R1: fused conv+fc+qsim kernel (whole-wave qsim, register-resident feat handoff)
//     + classifier replaced by a 16384-entry LUT over qout in [-1,1]
//       (classifier input is a single scalar; pre-sigmoid z is piecewise-linear).

#define WR_SZ 1856   // per-wave conv scratch floats
#define NL   16384   // LUT entries

// ---------------- LUT builder: z(t) for t on a uniform grid over [-1,1] ----------------
__global__ __launch_bounds__(256)
void build_lut(const float* __restrict__ w1, const float* __restrict__ b1,
               const float* __restrict__ w2, const float* __restrict__ b2,
               const float* __restrict__ w3, const float* __restrict__ b3,
               const float* __restrict__ w4, const float* __restrict__ b4,
               const float* __restrict__ w5, const float* __restrict__ b5,
               float* __restrict__ lut)
{
    __shared__ float hh[16][344];   // per entry: hA 184 + hB 144 (padded)
    const int tid = threadIdx.x;
    const int e = tid >> 4;         // entry slot in block
    const int w = tid & 15;
    const int idx = blockIdx.x * 16 + e;
    const float t = -1.f + 2.f * (float)idx / (float)(NL - 1);

    float* hA = hh[e];
    float* hB = hA + 184;

    // layer1: 1 -> 180
    #pragma unroll
    for (int tt = 0; tt < 12; ++tt) {
        int j = tt * 16 + w;
        if (j < 180) hA[j] = fmaxf(fmaf(t, w1[j], b1[j]), 0.f);
    }
    // layer2: 180 -> 140
    for (int tt = 0; tt < 9; ++tt) {
        int j = tt * 16 + w;
        int jj = (j < 140) ? j : 0;
        const float4* wrow = (const float4*)(w2 + jj * 180);
        float a0 = 0.f, a1 = 0.f, a2 = 0.f, a3 = 0.f;
        for (int kc = 0; kc < 45; ++kc) {
            float4 h4 = *(const float4*)(hA + kc * 4);
            float4 ww = wrow[kc];
            a0 = fmaf(h4.x, ww.x, a0); a1 = fmaf(h4.y, ww.y, a1);
            a2 = fmaf(h4.z, ww.z, a2); a3 = fmaf(h4.w, ww.w, a3);
        }
        if (j < 140) hB[j] = fmaxf((a0 + a1) + (a2 + a3) + b2[j], 0.f);
    }
    // layer3: 140 -> 100
    for (int tt = 0; tt < 7; ++tt) {
        int j = tt * 16 + w;
        int jj = (j < 100) ? j : 0;
        const float4* wrow = (const float4*)(w3 + jj * 140);
        float a0 = 0.f, a1 = 0.f, a2 = 0.f, a3 = 0.f;
        for (int kc = 0; kc < 35; ++kc) {
            float4 h4 = *(const float4*)(hB + kc * 4);
            float4 ww = wrow[kc];
            a0 = fmaf(h4.x, ww.x, a0); a1 = fmaf(h4.y, ww.y, a1);
            a2 = fmaf(h4.z, ww.z, a2); a3 = fmaf(h4.w, ww.w, a3);
        }
        if (j < 100) hA[j] = fmaxf((a0 + a1) + (a2 + a3) + b3[j], 0.f);
    }
    // layer4: 100 -> 50
    for (int tt = 0; tt < 4; ++tt) {
        int j = tt * 16 + w;
        int jj = (j < 50) ? j : 0;
        const float4* wrow = (const float4*)(w4 + jj * 100);
        float a0 = 0.f, a1 = 0.f, a2 = 0.f, a3 = 0.f;
        for (int kc = 0; kc < 25; ++kc) {
            float4 h4 = *(const float4*)(hA + kc * 4);
            float4 ww = wrow[kc];
            a0 = fmaf(h4.x, ww.x, a0); a1 = fmaf(h4.y, ww.y, a1);
            a2 = fmaf(h4.z, ww.z, a2); a3 = fmaf(h4.w, ww.w, a3);
        }
        if (j < 50) hB[j] = fmaxf((a0 + a1) + (a2 + a3) + b4[j], 0.f);
    }
    // layer5: 50 -> 1 (pre-sigmoid z)
    float p5 = 0.f;
    for (int k = w; k < 50; k += 16) p5 = fmaf(hB[k], w5[k], p5);
    #pragma unroll
    for (int m = 1; m < 16; m <<= 1) p5 += __shfl_xor(p5, m);
    if (w == 0) lut[idx] = p5 + b5[0];
}

// ---------------- main fused kernel ----------------
__global__ __launch_bounds__(256, 5)
void fused_all(const float* __restrict__ x,
               const float* __restrict__ c1w, const float* __restrict__ c1b,
               const float* __restrict__ c2w, const float* __restrict__ c2b,
               const float* __restrict__ c3w, const float* __restrict__ c3b,
               const float* __restrict__ fcw, const float* __restrict__ fcb,
               const float* __restrict__ qw,
               const float* __restrict__ lut,
               float* __restrict__ out, int B)
{
    __shared__ float wreg[4][WR_SZ];
    __shared__ float qc[56];
    __shared__ float qs[56];

    const int tid  = threadIdx.x;
    const int lane = tid & 63;
    const int wv   = tid >> 6;

    if (tid < 56) {
        float th = 0.5f * qw[tid];
        qc[tid] = cosf(th);
        qs[tid] = sinf(th);
    }
    __syncthreads();

    float* wr = wreg[wv];
    const int base = blockIdx.x * 16;

    for (int smp = 0; smp < 4; ++smp) {
        const int sample = base + wv * 4 + smp;
        if (sample >= B) break;

        float* c1p = wr;          // 768 = 3*16*16 (conv1 out, pad 1)
        float* pin = wr + 768;    // 1024 = 32*32  (input, pad 2)

        for (int i = lane; i < 1024; i += 64) pin[i] = 0.f;
        {
            const float4* xs = (const float4*)(x + (size_t)sample * 784);
            #pragma unroll
            for (int t = 0; t < 4; ++t) {
                int i4 = t * 64 + lane;
                if (i4 < 196) {
                    float4 v = xs[i4];
                    int r = i4 / 7;
                    int c = (i4 % 7) * 4;
                    float* dst = pin + (r + 2) * 32 + (c + 2);
                    dst[0] = v.x; dst[1] = v.y; dst[2] = v.z; dst[3] = v.w;
                }
            }
        }
        for (int i = lane; i < 768; i += 64) c1p[i] = 0.f;

        // ---- conv1: 1x28x28 -> 3x14x14, k5 s2 p2 ----
        #pragma unroll
        for (int t = 0; t < 4; ++t) {
            int p = t * 64 + lane;
            bool valid = p < 196;
            int pp = valid ? p : 0;
            int y = pp / 14, xx = pp % 14;
            const float* pr = pin + (2 * y) * 32 + 2 * xx;
            float win[25];
            #pragma unroll
            for (int ky = 0; ky < 5; ++ky)
                #pragma unroll
                for (int kx = 0; kx < 5; ++kx)
                    win[ky * 5 + kx] = pr[ky * 32 + kx];
            #pragma unroll
            for (int c = 0; c < 3; ++c) {
                float acc = c1b[c];
                #pragma unroll
                for (int k = 0; k < 25; ++k)
                    acc = fmaf(win[k], c1w[c * 25 + k], acc);
                if (valid) c1p[c * 256 + (y + 1) * 16 + (xx + 1)] = fmaxf(acc, 0.f);
            }
        }

        // ---- conv2: 3x14x14 -> 6x7x7, k3 s2 p1 ----
        float* c2p = wr + 768;   // 486 = 6*9*9 (pin dead)
        for (int i = lane; i < 486; i += 64) c2p[i] = 0.f;
        {
            int p = lane;
            bool valid = p < 49;
            int pp = valid ? p : 0;
            int y = pp / 7, xx = pp % 7;
            float acc[6];
            #pragma unroll
            for (int c = 0; c < 6; ++c) acc[c] = c2b[c];
            #pragma unroll
            for (int ic = 0; ic < 3; ++ic) {
                const float* pr = c1p + ic * 256 + (2 * y) * 16 + 2 * xx;
                float win[9];
                #pragma unroll
                for (int ky = 0; ky < 3; ++ky)
                    #pragma unroll
                    for (int kx = 0; kx < 3; ++kx)
                        win[ky * 3 + kx] = pr[ky * 16 + kx];
                #pragma unroll
                for (int c = 0; c < 6; ++c)
                    #pragma unroll
                    for (int k = 0; k < 9; ++k)
                        acc[c] = fmaf(win[k], c2w[c * 27 + ic * 9 + k], acc[c]);
            }
            if (valid) {
                #pragma unroll
                for (int c = 0; c < 6; ++c)
                    c2p[c * 81 + (y + 1) * 9 + (xx + 1)] = fmaxf(acc[c], 0.f);
            }
        }

        // ---- conv3: 6x7x7 -> 12x7x7, k3 s1 p1 ----
        float* c3 = wr + 1256;   // 588 = 12*49
        {
            int p = lane;
            bool valid = p < 49;
            int pp = valid ? p : 0;
            int y = pp / 7, xx = pp % 7;
            float acc[12];
            #pragma unroll
            for (int c = 0; c < 12; ++c) acc[c] = c3b[c];
            #pragma unroll
            for (int ic = 0; ic < 6; ++ic) {
                const float* pr = c2p + ic * 81 + y * 9 + xx;
                float win[9];
                #pragma unroll
                for (int ky = 0; ky < 3; ++ky)
                    #pragma unroll
                    for (int kx = 0; kx < 3; ++kx)
                        win[ky * 3 + kx] = pr[ky * 9 + kx];
                #pragma unroll
                for (int c = 0; c < 12; ++c)
                    #pragma unroll
                    for (int k = 0; k < 9; ++k)
                        acc[c] = fmaf(win[k], c3w[c * 54 + ic * 9 + k], acc[c]);
            }
            if (valid) {
                #pragma unroll
                for (int c = 0; c < 12; ++c)
                    c3[c * 49 + p] = fmaxf(acc[c], 0.f);
            }
        }

        // ---- adaptive pool (overlapping 4x4 bins) -> wr[0..48) ----
        {
            int o = lane;
            if (o < 48) {
                int c = o >> 2, i = (o >> 1) & 1, j = o & 1;
                int ri = i * 3, cj = j * 3;
                float s = 0.f;
                #pragma unroll
                for (int dy = 0; dy < 4; ++dy)
                    #pragma unroll
                    for (int dx = 0; dx < 4; ++dx)
                        s += c3[c * 49 + (ri + dy) * 7 + (cj + dx)];
                wr[o] = s * (1.f / 16.f);
            }
        }

        // ---- fc 48->256 + relu + L2-normalize; lane l keeps feats 4l..4l+3 in regs ----
        float st[4];
        {
            const int o0 = lane * 4;
            const float4* wr0 = (const float4*)(fcw + (o0 + 0) * 48);
            const float4* wr1 = (const float4*)(fcw + (o0 + 1) * 48);
            const float4* wr2 = (const float4*)(fcw + (o0 + 2) * 48);
            const float4* wr3 = (const float4*)(fcw + (o0 + 3) * 48);
            float a0 = 0.f, a1 = 0.f, a2 = 0.f, a3 = 0.f;
            #pragma unroll
            for (int kc = 0; kc < 12; ++kc) {
                float4 pv = *(const float4*)(wr + kc * 4);
                float4 q0 = wr0[kc], q1 = wr1[kc], q2 = wr2[kc], q3 = wr3[kc];
                a0 = fmaf(pv.x, q0.x, a0); a0 = fmaf(pv.y, q0.y, a0);
                a0 = fmaf(pv.z, q0.z, a0); a0 = fmaf(pv.w, q0.w, a0);
                a1 = fmaf(pv.x, q1.x, a1); a1 = fmaf(pv.y, q1.y, a1);
                a1 = fmaf(pv.z, q1.z, a1); a1 = fmaf(pv.w, q1.w, a1);
                a2 = fmaf(pv.x, q2.x, a2); a2 = fmaf(pv.y, q2.y, a2);
                a2 = fmaf(pv.z, q2.z, a2); a2 = fmaf(pv.w, q2.w, a2);
                a3 = fmaf(pv.x, q3.x, a3); a3 = fmaf(pv.y, q3.y, a3);
                a3 = fmaf(pv.w, q3.w, a3); a3 = fmaf(pv.z, q3.z, a3);
            }
            float4 fb = *(const float4*)(fcb + o0);
            float v0 = fmaxf(a0 + fb.x, 0.f);
            float v1 = fmaxf(a1 + fb.y, 0.f);
            float v2 = fmaxf(a2 + fb.z, 0.f);
            float v3 = fmaxf(a3 + fb.w, 0.f);
            float ss = v0 * v0 + v1 * v1 + v2 * v2 + v3 * v3;
            #pragma unroll
            for (int m = 1; m < 64; m <<= 1) ss += __shfl_xor(ss, m);
            float scale = 1.f / fmaxf(sqrtf(ss), 1e-12f);
            st[0] = v0 * scale; st[1] = v1 * scale;
            st[2] = v2 * scale; st[3] = v3 * scale;
        }

        // ---- qsim: amp index = 4*lane + j  (amp bits 7..2 = lane bits 5..0; bits 1..0 = j) ----
        for (int layer = 0; layer < 7; ++layer) {
            const float* qcl = qc + layer * 8;
            const float* qsl = qs + layer * 8;
            // rotations q=0..5 : lane-bit (5-q)
            #pragma unroll
            for (int q = 0; q < 6; ++q) {
                float c = qcl[q], s = qsl[q];
                const int lm = 1 << (5 - q);
                const float sg = (lane & lm) ? s : -s;
                #pragma unroll
                for (int j = 0; j < 4; ++j) {
                    float p = __shfl_xor(st[j], lm);
                    st[j] = fmaf(c, st[j], sg * p);
                }
            }
            // rotation q=6 : reg bit1  (pairs (0,2),(1,3))
            {
                float c = qcl[6], s = qsl[6];
                float v0 = st[0], v1 = st[2];
                st[0] = fmaf(c, v0, -s * v1);
                st[2] = fmaf(s, v0,  c * v1);
                v0 = st[1]; v1 = st[3];
                st[1] = fmaf(c, v0, -s * v1);
                st[3] = fmaf(s, v0,  c * v1);
            }
            // rotation q=7 : reg bit0  (pairs (0,1),(2,3))
            {
                float c = qcl[7], s = qsl[7];
                float v0 = st[0], v1 = st[1];
                st[0] = fmaf(c, v0, -s * v1);
                st[1] = fmaf(s, v0,  c * v1);
                v0 = st[2]; v1 = st[3];
                st[2] = fmaf(c, v0, -s * v1);
                st[3] = fmaf(s, v0,  c * v1);
            }
            // CNOT chain: ctrl bit(7-q), tgt bit(6-q)
            #pragma unroll
            for (int j = 0; j < 4; ++j) {   // q=0: ctrl lane b5, tgt lane b4
                float p = __shfl_xor(st[j], 16);
                st[j] = (lane & 32) ? p : st[j];
            }
            #pragma unroll
            for (int j = 0; j < 4; ++j) {   // q=1
                float p = __shfl_xor(st[j], 8);
                st[j] = (lane & 16) ? p : st[j];
            }
            #pragma unroll
            for (int j = 0; j < 4; ++j) {   // q=2
                float p = __shfl_xor(st[j], 4);
                st[j] = (lane & 8) ? p : st[j];
            }
            #pragma unroll
            for (int j = 0; j < 4; ++j) {   // q=3
                float p = __shfl_xor(st[j], 2);
                st[j] = (lane & 4) ? p : st[j];
            }
            #pragma unroll
            for (int j = 0; j < 4; ++j) {   // q=4
                float p = __shfl_xor(st[j], 1);
                st[j] = (lane & 2) ? p : st[j];
            }
            {   // q=5: ctrl lane b0, tgt reg bit1 (swap 0<->2, 1<->3)
                bool c5 = (lane & 1);
                float b0 = st[0], b1 = st[1], b2 = st[2], b3 = st[3];
                st[0] = c5 ? b2 : b0; st[2] = c5 ? b0 : b2;
                st[1] = c5 ? b3 : b1; st[3] = c5 ? b1 : b3;
            }
            {   // q=6: ctrl reg bit1, tgt reg bit0 (swap 2<->3)
                float t = st[2]; st[2] = st[3]; st[3] = t;
            }
        }

        // ---- measurement: qubit0 = amp bit7 = lane bit5 ----
        float part = st[0] * st[0] + st[1] * st[1] + st[2] * st[2] + st[3] * st[3];
        part = (lane & 32) ? -part : part;
        #pragma unroll
        for (int m = 1; m < 64; m <<= 1) part += __shfl_xor(part, m);

        if (lane == 0) {
            float qout = part;
            float u = (qout + 1.f) * 0.5f * (float)(NL - 1);
            int i0 = (int)floorf(u);
            i0 = (i0 < 0) ? 0 : ((i0 > NL - 2) ? NL - 2 : i0);
            float fr = u - (float)i0;
            float z0 = lut[i0], z1 = lut[i0 + 1];
            float z = fmaf(z1 - z0, fr, z0);
            out[sample] = 1.f / (1.f + expf(-z));
        }
    }
}

extern "C" void kernel_launch(void* const* d_in, const int* in_sizes, int n_in,
                              void* d_out, int out_size, void* d_ws, size_t ws_size,
                              hipStream_t stream) {
    const float* x   = (const float*)d_in[0];
    const float* c1w = (const float*)d_in[1];
    const float* c1b = (const float*)d_in[2];
    const float* c2w = (const float*)d_in[3];
    const float* c2b = (const float*)d_in[4];
    const float* c3w = (const float*)d_in[5];
    const float* c3b = (const float*)d_in[6];
    const float* fcw = (const float*)d_in[7];
    const float* fcb = (const float*)d_in[8];
    const float* qw  = (const float*)d_in[9];
    const float* w1  = (const float*)d_in[10];
    const float* b1  = (const float*)d_in[11];
    const float* w2  = (const float*)d_in[12];
    const float* b2  = (const float*)d_in[13];
    const float* w3  = (const float*)d_in[14];
    const float* b3  = (const float*)d_in[15];
    const float* w4  = (const float*)d_in[16];
    const float* b4  = (const float*)d_in[17];
    const float* w5  = (const float*)d_in[18];
    const float* b5  = (const float*)d_in[19];

    float* lut = (float*)d_ws;   // NL floats

    build_lut<<<dim3(NL / 16), dim3(256), 0, stream>>>(
        w1, b1, w2, b2, w3, b3, w4, b4, w5, b5, lut);

    int B = in_sizes[0] / 784;
    int grid = (B + 15) / 16;
    fused_all<<<dim3(grid), dim3(256), 0, stream>>>(
        x, c1w, c1b, c2w, c2b, c3w, c3b, fcw, fcb, qw, lut,
        (float*)d_out, B);
}